// Round 1
// baseline (409.031 us; speedup 1.0000x reference)
//
#include <hip/hip_runtime.h>
#include <math.h>

#define B_ 16
#define D_ 64
#define T_ 4096
#define K_ 1024
#define BT_ (B_*T_)

// output layout (flat f32, concatenated in return order)
#define ZQ_OFF   0
#define LOSS_OFF 4194304
#define IDX_OFF  4194305
#define PERP_OFF 4259841
#define HIST_OFF 4259842

// ws layout: float[0] = commit sum; float[1024..2048) = e_sq; int[2048..3072) = counts

__global__ __launch_bounds__(256) void esq_kernel(const float* __restrict__ emb,
                                                  float* __restrict__ e_sq) {
  int k = blockIdx.x * 256 + threadIdx.x;
  if (k < K_) {
    const float4* p = (const float4*)(emb + (size_t)k * D_);
    float s = 0.f;
#pragma unroll
    for (int i = 0; i < 16; ++i) {
      float4 v = p[i];
      s += v.x * v.x + v.y * v.y + v.z * v.z + v.w * v.w;
    }
    e_sq[k] = s;
  }
}

__device__ __forceinline__ double dist64(const float* x, const float* __restrict__ emb, int k) {
  const float* e = emb + (size_t)k * D_;
  double s = 0.0, dot = 0.0;
#pragma unroll
  for (int d = 0; d < D_; ++d) {
    double ev = (double)e[d];
    s += ev * ev;
    dot += (double)x[d] * ev;
  }
  return s - 2.0 * dot;
}

__global__ __launch_bounds__(256) void vq_main(
    const float* __restrict__ z_e, const float* __restrict__ emb,
    const float* __restrict__ e_sq, float* __restrict__ out,
    float* __restrict__ commit_ws, int* __restrict__ counts) {
  __shared__ float s_b1[4][64];
  __shared__ float s_b2[4][64];
  __shared__ int   s_k1[4][64];
  __shared__ int   s_k2[4][64];

  const int lane = threadIdx.x & 63;
  const int wave = threadIdx.x >> 6;
  const int row  = blockIdx.x * 64 + lane;          // 0..BT_
  const int b = row >> 12;                          // row / T_
  const int t = row & (T_ - 1);                     // row % T_
  const float* zp = z_e + ((size_t)b * D_) * T_ + t;

  // x in registers (coalesced loads: consecutive lanes -> consecutive t)
  float x[D_];
#pragma unroll
  for (int d = 0; d < D_; ++d) x[d] = zp[(size_t)d * T_];

  // each wave scans a wave-uniform K-range of 256 codes
  const int k0 = __builtin_amdgcn_readfirstlane(wave * 256);

  float b1 = 1e30f, b2 = 1e30f;
  int   k1 = 0,     k2 = 0;
  for (int kk = 0; kk < 256; ++kk) {
    const int k = k0 + kk;
    const float4* e4 = (const float4*)(emb + (size_t)k * D_);
    float a0 = 0.f, a1 = 0.f, a2 = 0.f, a3 = 0.f;
#pragma unroll
    for (int i = 0; i < 16; ++i) {
      float4 v = e4[i];
      a0 = fmaf(x[4 * i + 0], v.x, a0);
      a1 = fmaf(x[4 * i + 1], v.y, a1);
      a2 = fmaf(x[4 * i + 2], v.z, a2);
      a3 = fmaf(x[4 * i + 3], v.w, a3);
    }
    const float dist = e_sq[k] - 2.0f * ((a0 + a1) + (a2 + a3));
    if (dist < b1) { b2 = b1; k2 = k1; b1 = dist; k1 = k; }
    else if (dist < b2) { b2 = dist; k2 = k; }
  }
  s_b1[wave][lane] = b1; s_k1[wave][lane] = k1;
  s_b2[wave][lane] = b2; s_k2[wave][lane] = k2;
  __syncthreads();

  if (wave == 0) {
    // merge the 4 waves' top-2 candidates (wave order = ascending k ranges,
    // strict < keeps the first/lowest-index minimum like np.argmin)
    float bv = 1e30f, sv = 1e30f;
    int   bk = 0,     sk = 0;
#pragma unroll
    for (int w = 0; w < 4; ++w) {
      float v1 = s_b1[w][lane]; int i1 = s_k1[w][lane];
      float v2 = s_b2[w][lane]; int i2 = s_k2[w][lane];
      if (v1 < bv || (v1 == bv && i1 < bk)) { sv = bv; sk = bk; bv = v1; bk = i1; }
      else if (v1 < sv || (v1 == sv && i1 < sk)) { sv = v1; sk = i1; }
      if (v2 < bv || (v2 == bv && i2 < bk)) { sv = bv; sk = bk; bv = v2; bk = i2; }
      else if (v2 < sv || (v2 == sv && i2 < sk)) { sv = v2; sk = i2; }
    }

    // near-tie: re-decide in f64 (insurance against fp32 argmin flips vs np ref)
    if (sv - bv < 1e-3f) {
      double db = dist64(x, emb, bk);
      double ds = dist64(x, emb, sk);
      if (ds < db || (ds == db && sk < bk)) {
        bk = sk;
        bv = sv;
      }
    }

    // z_q_st = embedding[bk] scattered to (b, d, t) layout
    const float4* eq = (const float4*)(emb + (size_t)bk * D_);
    float* op = out + ((size_t)b * D_) * T_ + t;
#pragma unroll
    for (int i = 0; i < 16; ++i) {
      float4 v = eq[i];
      op[(size_t)(4 * i + 0) * T_] = v.x;
      op[(size_t)(4 * i + 1) * T_] = v.y;
      op[(size_t)(4 * i + 2) * T_] = v.z;
      op[(size_t)(4 * i + 3) * T_] = v.w;
    }

    out[IDX_OFF + row] = (float)bk;
    atomicAdd(&counts[bk], 1);

    // commit contribution: ||x - e||^2 = x^2 + (e_sq - 2 dot) = x^2 + bv
    float xsq = 0.f;
#pragma unroll
    for (int d = 0; d < D_; ++d) xsq = fmaf(x[d], x[d], xsq);
    float c = xsq + bv;
#pragma unroll
    for (int off = 32; off; off >>= 1) c += __shfl_down(c, off, 64);
    if (lane == 0) atomicAdd(commit_ws, c);
  }
}

__global__ __launch_bounds__(1024) void finalize_kernel(
    const int* __restrict__ counts, const float* __restrict__ commit_ws,
    float* __restrict__ out) {
  __shared__ float red[1024];
  const int k = threadIdx.x;
  const int c = counts[k];
  const float p = (float)c / (float)BT_;   // total is always BT_ (all rows assigned)
  out[HIST_OFF + k] = p;
  red[k] = (c > 0) ? p * logf(p) : 0.0f;
  __syncthreads();
  for (int s = 512; s > 0; s >>= 1) {
    if (k < s) red[k] += red[k + s];
    __syncthreads();
  }
  if (k == 0) {
    out[PERP_OFF] = expf(-red[0]);
    out[LOSS_OFF] = 0.25f * commit_ws[0] / (float)(B_ * D_ * T_);
  }
}

extern "C" void kernel_launch(void* const* d_in, const int* in_sizes, int n_in,
                              void* d_out, int out_size, void* d_ws, size_t ws_size,
                              hipStream_t stream) {
  const float* z_e = (const float*)d_in[0];
  const float* emb = (const float*)d_in[1];
  float* out = (float*)d_out;

  float* wsf       = (float*)d_ws;
  float* commit_ws = wsf;                  // 1 float
  float* e_sq      = wsf + 1024;           // K floats
  int*   counts    = ((int*)d_ws) + 2048;  // K ints

  hipMemsetAsync(d_ws, 0, 3072 * sizeof(float), stream);
  esq_kernel<<<4, 256, 0, stream>>>(emb, e_sq);
  vq_main<<<BT_ / 64, 256, 0, stream>>>(z_e, emb, e_sq, out, commit_ws, counts);
  finalize_kernel<<<1, 1024, 0, stream>>>(counts, commit_ws, out);
}

// Round 2
// 169.538 us; speedup vs baseline: 2.4126x; 2.4126x over previous
//
#include <hip/hip_runtime.h>
#include <hip/hip_bf16.h>
#include <math.h>

#define B_ 16
#define D_ 64
#define T_ 4096
#define K_ 1024
#define BT_ (B_*T_)

// output layout (flat f32, concatenated in return order)
#define ZQ_OFF   0
#define LOSS_OFF 4194304
#define IDX_OFF  4194305
#define PERP_OFF 4259841
#define HIST_OFF 4259842

typedef __attribute__((ext_vector_type(8))) short bf16x8;
typedef __attribute__((ext_vector_type(4))) float f32x4;

__device__ __forceinline__ unsigned umin_(unsigned a, unsigned b){ return a < b ? a : b; }
__device__ __forceinline__ unsigned umax_(unsigned a, unsigned b){ return a > b ? a : b; }

__device__ __forceinline__ ushort f2bf(float x) {
  __hip_bfloat16 h = __float2bfloat16(x);
  return *(ushort*)&h;
}
__device__ __forceinline__ float bf2f(ushort u) {
  __hip_bfloat16 h; *(ushort*)&h = u;
  return __bfloat162float(h);
}

// ---- prep: emb f32 -> (ebh, ebl) bf16 split + e_sq ----
// 4096 threads: 1024 codes x 4 chunks of 16 dims
__global__ __launch_bounds__(256) void prep_kernel(
    const float* __restrict__ emb, float* __restrict__ e_sq,
    ushort* __restrict__ ebh, ushort* __restrict__ ebl) {
  const int tid = blockIdx.x * 256 + threadIdx.x;
  const int k = tid >> 2, q = tid & 3;
  const float4* p = (const float4*)(emb + (size_t)k * D_ + q * 16);
  bf16x8 vh[2], vl[2];
  float s = 0.f;
#pragma unroll
  for (int i = 0; i < 4; ++i) {
    float4 v = p[i];
    float xs[4] = {v.x, v.y, v.z, v.w};
#pragma unroll
    for (int j = 0; j < 4; ++j) {
      float x = xs[j];
      ushort hb = f2bf(x);
      ushort lb = f2bf(x - bf2f(hb));
      vh[i >> 1][(i & 1) * 4 + j] = (short)hb;
      vl[i >> 1][(i & 1) * 4 + j] = (short)lb;
      s = fmaf(x, x, s);
    }
  }
  size_t off = (size_t)k * D_ + q * 16;
  *(bf16x8*)(ebh + off) = vh[0];
  *(bf16x8*)(ebh + off + 8) = vh[1];
  *(bf16x8*)(ebl + off) = vl[0];
  *(bf16x8*)(ebl + off + 8) = vl[1];
  s += __shfl_xor(s, 1, 64);
  s += __shfl_xor(s, 2, 64);
  if (q == 0) e_sq[k] = s;
}

__device__ double dist64row(const float* __restrict__ zb, int r,
                            const float* __restrict__ emb, int k) {
  double s = 0.0, dot = 0.0;
#pragma unroll
  for (int d = 0; d < D_; ++d) {
    double e = (double)emb[(size_t)k * D_ + d];
    double x = (double)zb[(size_t)d * T_ + r];
    s += e * e;
    dot += x * e;
  }
  return s - 2.0 * dot;
}

// ---- main: 32 rows/block, 4 waves x 256-code quadrant, MFMA bf16-split ----
__global__ __launch_bounds__(256) void vq_mfma(
    const float* __restrict__ z_e, const float* __restrict__ emb_f32,
    const float* __restrict__ e_sq, const ushort* __restrict__ ebh,
    const ushort* __restrict__ ebl, float* __restrict__ out,
    float* __restrict__ commit_ws, int* __restrict__ counts) {
  __shared__ ushort Ah[32 * 64];
  __shared__ ushort Al[32 * 64];
  __shared__ unsigned mrg1[4][32];
  __shared__ unsigned mrg2[4][32];
  __shared__ int idx_sh[32];
  __shared__ float cred[256];

  const int tid = threadIdx.x;
  const int lane = tid & 63, wave = tid >> 6;
  const int b = blockIdx.x >> 7;
  const int t0 = (blockIdx.x & 127) << 5;
  const float* zbase = z_e + ((size_t)b * D_) * T_ + t0;

  // Phase 0: stage A tile (32 rows x 64 d) as bf16 hi/lo, XOR-swizzled rows
  {
    const int r = tid & 31, d0 = (tid >> 5) * 8;
    bf16x8 vh, vl;
#pragma unroll
    for (int j = 0; j < 8; ++j) {
      float x = zbase[(size_t)(d0 + j) * T_ + r];
      ushort hb = f2bf(x);
      vh[j] = (short)hb;
      vl[j] = (short)f2bf(x - bf2f(hb));
    }
    const int off = (r * 128 + d0 * 2) ^ ((r & 7) << 4);  // byte offset
    *(bf16x8*)((char*)Ah + off) = vh;
    *(bf16x8*)((char*)Al + off) = vl;
  }
  __syncthreads();

  // A fragments to registers (reused across all 16 slabs): [rowfrag][kstep]
  bf16x8 afh[2][2], afl[2][2];
  {
    const int ar = lane & 15;
    const int aks = (lane >> 4) * 8;
#pragma unroll
    for (int f = 0; f < 2; ++f)
#pragma unroll
      for (int ks = 0; ks < 2; ++ks) {
        const int row = f * 16 + ar;
        const int col = ks * 32 + aks;
        const int off = (row * 128 + col * 2) ^ ((row & 7) << 4);
        afh[f][ks] = *(bf16x8*)((char*)Ah + off);
        afl[f][ks] = *(bf16x8*)((char*)Al + off);
      }
  }

  const int cw0 = wave * 256;  // wave's code base
  // per-lane B element offset: code row = cw0 + (lane&15), k-slice (lane>>4)*8
  const size_t boff = (size_t)(cw0 + (lane & 15)) * D_ + (lane >> 4) * 8;

  unsigned b1[2][4], b2[2][4];
#pragma unroll
  for (int f = 0; f < 2; ++f)
#pragma unroll
    for (int r = 0; r < 4; ++r) { b1[f][r] = 0xFFFFFFFFu; b2[f][r] = 0xFFFFFFFFu; }

  bf16x8 cbh[2][2], cbl[2][2];
  float cesq[2];
#define LOADB(s, buf)                                                   \
  { size_t o = boff + (size_t)(s) * 16 * D_;                            \
    cbh[buf][0] = *(const bf16x8*)(ebh + o);                            \
    cbh[buf][1] = *(const bf16x8*)(ebh + o + 32);                       \
    cbl[buf][0] = *(const bf16x8*)(ebl + o);                            \
    cbl[buf][1] = *(const bf16x8*)(ebl + o + 32);                       \
    cesq[buf] = e_sq[cw0 + (s) * 16 + (lane & 15)]; }

  LOADB(0, 0);
#pragma unroll
  for (int s = 0; s < 16; ++s) {
    const int cur = s & 1, nxt = cur ^ 1;
    if (s < 15) LOADB(s + 1, nxt);
    f32x4 a0 = {0.f, 0.f, 0.f, 0.f}, a1 = {0.f, 0.f, 0.f, 0.f};
    // hi*hi (both ksteps)
    a0 = __builtin_amdgcn_mfma_f32_16x16x32_bf16(afh[0][0], cbh[cur][0], a0, 0, 0, 0);
    a1 = __builtin_amdgcn_mfma_f32_16x16x32_bf16(afh[1][0], cbh[cur][0], a1, 0, 0, 0);
    a0 = __builtin_amdgcn_mfma_f32_16x16x32_bf16(afh[0][1], cbh[cur][1], a0, 0, 0, 0);
    a1 = __builtin_amdgcn_mfma_f32_16x16x32_bf16(afh[1][1], cbh[cur][1], a1, 0, 0, 0);
    // lo*hi
    a0 = __builtin_amdgcn_mfma_f32_16x16x32_bf16(afl[0][0], cbh[cur][0], a0, 0, 0, 0);
    a1 = __builtin_amdgcn_mfma_f32_16x16x32_bf16(afl[1][0], cbh[cur][0], a1, 0, 0, 0);
    a0 = __builtin_amdgcn_mfma_f32_16x16x32_bf16(afl[0][1], cbh[cur][1], a0, 0, 0, 0);
    a1 = __builtin_amdgcn_mfma_f32_16x16x32_bf16(afl[1][1], cbh[cur][1], a1, 0, 0, 0);
    // hi*lo
    a0 = __builtin_amdgcn_mfma_f32_16x16x32_bf16(afh[0][0], cbl[cur][0], a0, 0, 0, 0);
    a1 = __builtin_amdgcn_mfma_f32_16x16x32_bf16(afh[1][0], cbl[cur][0], a1, 0, 0, 0);
    a0 = __builtin_amdgcn_mfma_f32_16x16x32_bf16(afh[0][1], cbl[cur][1], a0, 0, 0, 0);
    a1 = __builtin_amdgcn_mfma_f32_16x16x32_bf16(afh[1][1], cbl[cur][1], a1, 0, 0, 0);

    const unsigned code = (unsigned)(cw0 + s * 16 + (lane & 15));
#pragma unroll
    for (int f = 0; f < 2; ++f) {
#pragma unroll
      for (int r = 0; r < 4; ++r) {
        float av = (f == 0) ? a0[r] : a1[r];
        float dist = fmaf(av, -2.0f, cesq[cur]);
        unsigned u = __float_as_uint(dist);
        unsigned sk = u ^ (unsigned)(((int)u >> 31) | 0x80000000);
        unsigned key = (sk & 0xFFFFFC00u) | code;
        unsigned t = umax_(b1[f][r], key);
        b1[f][r] = umin_(b1[f][r], key);
        b2[f][r] = umin_(b2[f][r], t);
      }
    }
  }
#undef LOADB

  // cross-lane top-2 merge across the 16 col-slots (lanes differing in bits 0..3)
#pragma unroll
  for (int m = 1; m < 16; m <<= 1) {
#pragma unroll
    for (int f = 0; f < 2; ++f)
#pragma unroll
      for (int r = 0; r < 4; ++r) {
        unsigned o1 = (unsigned)__shfl_xor((int)b1[f][r], m, 64);
        unsigned o2 = (unsigned)__shfl_xor((int)b2[f][r], m, 64);
        unsigned t = umax_(b1[f][r], o1);
        b1[f][r] = umin_(b1[f][r], o1);
        b2[f][r] = umin_(umin_(b2[f][r], o2), t);
      }
  }
  if ((lane & 15) == 0) {
    const int g = lane >> 4;
#pragma unroll
    for (int f = 0; f < 2; ++f)
#pragma unroll
      for (int r = 0; r < 4; ++r) {
        const int row = f * 16 + g * 4 + r;
        mrg1[wave][row] = b1[f][r];
        mrg2[wave][row] = b2[f][r];
      }
  }
  __syncthreads();

  // Phase 2: merge 4 wave-quadrants per row, tie-break in f64, emit index
  if (tid < 32) {
    const int r = tid;
    unsigned B1 = 0xFFFFFFFFu, B2 = 0xFFFFFFFFu;
#pragma unroll
    for (int w = 0; w < 4; ++w) {
      unsigned o1 = mrg1[w][r], o2 = mrg2[w][r];
      unsigned t = umax_(B1, o1);
      B1 = umin_(B1, o1);
      B2 = umin_(umin_(B2, o2), t);
    }
    int i1 = (int)(B1 & 1023u);
    const int i2 = (int)(B2 & 1023u);
    // close call (within 8 quantization buckets) -> exact f64 decision
    if ((B2 & ~1023u) - (B1 & ~1023u) <= (8u << 10)) {
      double d1 = dist64row(zbase, r, emb_f32, i1);
      double d2 = dist64row(zbase, r, emb_f32, i2);
      if (d2 < d1 || (d2 == d1 && i2 < i1)) i1 = i2;
    }
    idx_sh[r] = i1;
    out[IDX_OFF + b * T_ + t0 + r] = (float)i1;
    atomicAdd(&counts[i1], 1);
  }
  __syncthreads();

  // Phase 3: gather z_q (exact f32), write out, exact commit-loss partial
  {
    const int r = tid & 31, d0 = (tid >> 5) * 8;
    const int k = idx_sh[r];
    const float* ep = emb_f32 + (size_t)k * D_ + d0;
    float c = 0.f;
#pragma unroll
    for (int j = 0; j < 8; ++j) {
      float e = ep[j];
      float x = zbase[(size_t)(d0 + j) * T_ + r];
      out[ZQ_OFF + ((size_t)b * D_ + d0 + j) * T_ + t0 + r] = e;
      float df = x - e;
      c = fmaf(df, df, c);
    }
    cred[tid] = c;
  }
  __syncthreads();
  for (int s = 128; s > 0; s >>= 1) {
    if (tid < s) cred[tid] += cred[tid + s];
    __syncthreads();
  }
  if (tid == 0) atomicAdd(commit_ws, cred[0]);
}

__global__ __launch_bounds__(1024) void finalize_kernel(
    const int* __restrict__ counts, const float* __restrict__ commit_ws,
    float* __restrict__ out) {
  __shared__ float red[1024];
  const int k = threadIdx.x;
  const int c = counts[k];
  const float p = (float)c / (float)BT_;
  out[HIST_OFF + k] = p;
  red[k] = (c > 0) ? p * logf(p) : 0.0f;
  __syncthreads();
  for (int s = 512; s > 0; s >>= 1) {
    if (k < s) red[k] += red[k + s];
    __syncthreads();
  }
  if (k == 0) {
    out[PERP_OFF] = expf(-red[0]);
    out[LOSS_OFF] = 0.25f * commit_ws[0] / (float)(B_ * D_ * T_);
  }
}

extern "C" void kernel_launch(void* const* d_in, const int* in_sizes, int n_in,
                              void* d_out, int out_size, void* d_ws, size_t ws_size,
                              hipStream_t stream) {
  const float* z_e = (const float*)d_in[0];
  const float* emb = (const float*)d_in[1];
  float* out = (float*)d_out;

  // ws layout (bytes): [0] commit f32; [4096] counts int[1024]; [8192] e_sq f32[1024];
  // [12288] ebh ushort[65536]; [143360] ebl ushort[65536]  (~272 KB total)
  float* commit_ws = (float*)d_ws;
  int* counts = (int*)((char*)d_ws + 4096);
  float* e_sq = (float*)((char*)d_ws + 8192);
  ushort* ebh = (ushort*)((char*)d_ws + 12288);
  ushort* ebl = (ushort*)((char*)d_ws + 12288 + 131072);

  hipMemsetAsync(d_ws, 0, 8192, stream);
  prep_kernel<<<16, 256, 0, stream>>>(emb, e_sq, ebh, ebl);
  vq_mfma<<<BT_ / 32, 256, 0, stream>>>(z_e, emb, e_sq, ebh, ebl, out, commit_ws, counts);
  finalize_kernel<<<1, 1024, 0, stream>>>(counts, commit_ws, out);
}